// Round 13
// baseline (243.655 us; speedup 1.0000x reference)
//
#include <hip/hip_runtime.h>
#include <stdint.h>

// Problem constants (match reference)
#define NP 32    // num networks (P)
#define NH 128   // hidden (H)
#define NB 32    // batch (B)
#define NT 256   // time (T)
#define FH 512   // 4*H

typedef __attribute__((ext_vector_type(4))) float float4_t;
typedef __attribute__((ext_vector_type(8))) __bf16 bf16x8;
typedef __attribute__((ext_vector_type(4))) __bf16 bf16x4;

static __device__ __forceinline__ float4_t mfma_bf16(bf16x8 a, bf16x8 b, float4_t c) {
  return __builtin_amdgcn_mfma_f32_16x16x32_bf16(a, b, c, 0, 0, 0);
}

#define LOG2E 1.4426950408889634f

// Raw workgroup barrier: drains LDS ops only (cross-wave h visibility), does
// NOT drain vmcnt — pending global loads/stores stay in flight across it.
#define BAR() __asm__ volatile("s_waitcnt lgkmcnt(0)\n\ts_barrier" ::: "memory")

// ---------------------------------------------------------------------------
// R21: R19 (best, 163.8us) + HEAD-ECTOMY. R20 post-mortem: tail-issued
// roots removed the ds_read-latency cover at the step top (MfmaUtil 47->41,
// +16us) — R19's schedule (roots at top cover ds; x-load mid-step = full
// shadow) is the local optimum of this family; both perturbations (R18,
// R20) lost. FROZEN.
// Remaining exposure item: the rotating head wave runs 4 extra MFMAs,
// scoreboard-waits for their results, stores, and arrives ~150-200 cyc
// late at BAR — convoying all waves, every step. Fix (R14-proven pattern,
// now without the spill confound): per-thread async h-dump to ws
// (global_store_short flies across the lgkm-only BAR; steady-state ~1
// outstanding), loop body fully wave-uniform, head computed in an
// in-kernel epilogue (Wout staged in LDS, f32 dot over the L2-resident
// dump, ~2-4us). Also frees wof/bo from loop registers.
// WRITE_SIZE will show ~67MB: that is INTENDED dump traffic (~10us BW,
// hidden), not spill — spill would show VGPR=64 + FETCH blowup (R9-R11).
// SESSION RULES: launch_bounds 2nd arg never !=1 (R9-R11 spill death);
// waves_per_eu(2,2) = trusted 256-reg knob (R15); no DS ops in loop beyond
// h write/read (R5); M=4/256 blocks geometrically forced (R12/R14);
// refuted: co-residency (R14), SB-stagger (R17), mid-chain acts (R16),
// tail roots (R18/R20); VALU cuts below ~35% busy buy nothing (R19).
// ---------------------------------------------------------------------------

// Prepass: X f32 -> bf16 into ws (same [B][T][P] layout). 262144 elems.
__global__ __launch_bounds__(512, 1) void xcvt(
    const float* __restrict__ X, __bf16* __restrict__ Xb)
{
  const int i = (blockIdx.x * 512 + threadIdx.x) * 4;
  float4_t v = *(const float4_t*)(X + i);
  bf16x4 o;
#pragma unroll
  for (int j = 0; j < 4; ++j) o[j] = (__bf16)v[j];
  *(bf16x4*)(Xb + i) = o;
}

__global__ __attribute__((amdgpu_flat_work_group_size(512, 512),
                          amdgpu_waves_per_eu(2, 2)))
void clstm_fused9(
    const __bf16* __restrict__ Xb, const float* __restrict__ Wih,
    const float* __restrict__ Whh, const float* __restrict__ bih,
    const float* __restrict__ bhh, const float* __restrict__ Wout,
    const float* __restrict__ bout, float* __restrict__ out,
    __bf16* __restrict__ wsH)
{
  // XCD swizzle (R17-proven): blocks {n, n+32, ...} share net n and land on
  // one XCD -> weights L2-resident.
  const int net = blockIdx.x & 31, bq = blockIdx.x >> 5;
  const int tid = threadIdx.x;
  const int w = tid >> 6, lane = tid & 63;
  const int quad = lane >> 4, l16 = lane & 15;

  // h A-fragments, double buffered, 4 DISTINCT rows: [buf][kc][kquad][m<4][j]
  __shared__ __bf16 hfrag[2][4][4][4][8];   // 2 KB total

  { ((int*)hfrag)[tid] = 0; }   // h0 = 0, both buffers
  __syncthreads();

  // ---- load weights into register B-fragments (one-time) ----
  // B-frag layout for 16x16x32: lane holds B[k = quad*8 + j][n = l16].
  bf16x8 bfrag[4][5];
  float4_t bias4[4];
#pragma unroll
  for (int g = 0; g < 4; ++g) {
    const float scale = (g == 2) ? (-2.0f*LOG2E) : (-LOG2E);
    const int col = g*NH + w*16 + l16;
#pragma unroll
    for (int kc = 0; kc < 5; ++kc) {
      const float* src = (kc == 0) ? (Wih + ((size_t)net*FH + col)*NP + quad*8)
                                   : (Whh + ((size_t)net*FH + col)*NH + (kc-1)*32 + quad*8);
      bf16x8 bf;
#pragma unroll
      for (int j = 0; j < 8; ++j) bf[j] = (__bf16)(src[j] * scale);
      bfrag[g][kc] = bf;
    }
    const float b = (bih[net*FH + col] + bhh[net*FH + col]) * scale;
    bias4[g] = (float4_t){b, b, b, b};
  }

  // c state, PRE-SCALED by -2log2e (saves a mul on the h critical chain)
  float cs = 0.f;
  const float S2 = -2.0f*LOG2E;

  // x source: A-row l16 -> batch bq*4 + (l16>>2)  (dup-grouped rows)
  int xoff = (bq*4 + (l16 >> 2))*(NT*NP) + quad*8;

  // h write coords for unit u = w*16 + l16; batch row = quad (unchanged)
  const int kcp = w >> 1, q2 = ((w & 1) << 1) | (l16 >> 3), jj = l16 & 7;

  // h-dump: per-block 256KB region, layout [t][batch][unit] (bf16).
  // Each thread owns ONE (batch=quad, unit=w*16+l16) cell per step.
  __bf16* wsHb = wsH + (size_t)blockIdx.x * (NT * 4 * NH);
  int hoff = quad * NH + w * 16 + l16;

  // prologue: ax = x(0)
  bf16x8 ax = *(const bf16x8*)(Xb + xoff);
  xoff += NP;

// ---- one step; RD/WR literal (unroll x2). ax enters holding x(T_);
// x(T_+1) is loaded mid-step and consumed at the NEXT step's top (full
// shadow). Loop body is fully wave-uniform (no head, no branches except
// the guarded x load). ----
#define STEP(RD, WR, T_)                                                      \
  do {                                                                        \
    /* h A-frags (row = l16>>2; 4-lane same-address broadcast) */             \
    bf16x8 ah0 = *(const bf16x8*)&hfrag[RD][0][quad][l16 >> 2][0];            \
    bf16x8 ah1 = *(const bf16x8*)&hfrag[RD][1][quad][l16 >> 2][0];            \
    bf16x8 ah2 = *(const bf16x8*)&hfrag[RD][2][quad][l16 >> 2][0];            \
    bf16x8 ah3 = *(const bf16x8*)&hfrag[RD][3][quad][l16 >> 2][0];            \
    /* x-MFMAs first: chain roots (C = bias), no LDS dep — fill ds wait */    \
    float4_t a0 = mfma_bf16(ax, bfrag[0][0], bias4[0]);                       \
    float4_t a1 = mfma_bf16(ax, bfrag[1][0], bias4[1]);                       \
    float4_t a2 = mfma_bf16(ax, bfrag[2][0], bias4[2]);                       \
    float4_t a3 = mfma_bf16(ax, bfrag[3][0], bias4[3]);                       \
    /* x reload for t+1 (guarded; ax dead after the roots above) */           \
    if ((T_) + 1 < NT)                                                        \
      ax = *(const bf16x8*)(Xb + xoff);                                       \
    xoff += NP;                                                               \
    /* h-MFMAs: 4 serial chains, round-robin (4-way ILP) */                   \
    a0 = mfma_bf16(ah0, bfrag[0][1], a0);                                     \
    a1 = mfma_bf16(ah0, bfrag[1][1], a1);                                     \
    a2 = mfma_bf16(ah0, bfrag[2][1], a2);                                     \
    a3 = mfma_bf16(ah0, bfrag[3][1], a3);                                     \
    a0 = mfma_bf16(ah1, bfrag[0][2], a0);                                     \
    a1 = mfma_bf16(ah1, bfrag[1][2], a1);                                     \
    a2 = mfma_bf16(ah1, bfrag[2][2], a2);                                     \
    a3 = mfma_bf16(ah1, bfrag[3][2], a3);                                     \
    a0 = mfma_bf16(ah2, bfrag[0][3], a0);                                     \
    a1 = mfma_bf16(ah2, bfrag[1][3], a1);                                     \
    a2 = mfma_bf16(ah2, bfrag[2][3], a2);                                     \
    a3 = mfma_bf16(ah2, bfrag[3][3], a3);                                     \
    a0 = mfma_bf16(ah3, bfrag[0][4], a0);                                     \
    a1 = mfma_bf16(ah3, bfrag[1][4], a1);                                     \
    a2 = mfma_bf16(ah3, bfrag[2][4], a2);                                     \
    a3 = mfma_bf16(ah3, bfrag[3][4], a3);                                     \
    /* acts: gv = acc[0] (dup-grouped rows — no cndmask select) */            \
    float ei = __builtin_amdgcn_exp2f(a0[0]);                                 \
    float ig = __builtin_amdgcn_rcpf(1.0f + ei);          /* sigmoid(i) */    \
    float ef = __builtin_amdgcn_exp2f(a1[0]);                                 \
    float fg = __builtin_amdgcn_rcpf(1.0f + ef);          /* sigmoid(f) */    \
    float eg = __builtin_amdgcn_exp2f(fminf(a2[0], 126.0f));                  \
    float rg = __builtin_amdgcn_rcpf(1.0f + eg);                              \
    float t0 = S2 * rg;                                                       \
    float gg2 = t0 - t0 * eg;                             /* tanh(g)*S2 */    \
    float eo = __builtin_amdgcn_exp2f(a3[0]);                                 \
    float og = __builtin_amdgcn_rcpf(1.0f + eo);          /* sigmoid(o) */    \
    cs = fg * cs + ig * gg2;                              /* c * S2 */        \
    float ec = __builtin_amdgcn_exp2f(fminf(cs, 126.0f));                     \
    float rc = __builtin_amdgcn_rcpf(1.0f + ec);                              \
    float h_ = og * (rc - ec * rc);                       /* o*tanh(c) */     \
    /* write h': LDS (next step's A-frags) + async global dump.           */  \
    /* The store is vmcnt-tracked and NOT drained by BAR — it flies. */       \
    hfrag[WR][kcp][q2][quad][jj] = (__bf16)h_;                                \
    wsHb[hoff] = (__bf16)h_;                                                  \
    hoff += 4 * NH;                                                           \
    BAR();                                                                    \
  } while (0)

  for (int t = 0; t < NT; t += 2) {
    STEP(0, 1, t);
    STEP(1, 0, t + 1);
  }
#undef STEP

  // ---- epilogue: 1x1-conv head from the h dump (f32 VALU) ----
  // BAR never drained vmcnt; reads below consume OTHER threads' global
  // stores -> drain own stores, fence, block-sync (R14-proven sequence).
  __asm__ volatile("s_waitcnt vmcnt(0)" ::: "memory");
  __threadfence();
  __syncthreads();
  // stage Wout[net] (128 f32) in LDS (hfrag storage reused)
  float* ldsW = (float*)&hfrag[0][0][0][0][0];
  if (tid < NH) ldsW[tid] = Wout[net*NH + tid];
  __syncthreads();

  const float bo = bout[net];
  // 1024 (t, batch) items over 512 threads, 2 each.
#pragma unroll
  for (int rep = 0; rep < 2; ++rep) {
    const int idx = tid + rep * 512;
    const int tt = idx >> 2, b = idx & 3;
    const __bf16* hp = wsHb + tt * (4 * NH) + b * NH;
    float s = bo;
#pragma unroll
    for (int kc = 0; kc < 16; ++kc) {
      bf16x8 h8 = *(const bf16x8*)(hp + kc * 8);
#pragma unroll
      for (int j = 0; j < 8; ++j)
        s += (float)h8[j] * ldsW[kc * 8 + j];    // broadcast LDS read
    }
    out[(size_t)(bq * 4 + b) * (NT * NP) + tt * NP + net] = s;
  }
}

// ---------------------------------------------------------------------------
// Fallback (ws too small): R8 kernel verbatim — M=4 / 256 blocks, fused
// head, f32 X loads, 219us rocprof. No workspace use.
// ---------------------------------------------------------------------------
__global__ __launch_bounds__(512, 1) void clstm_fused_fb(
    const float* __restrict__ X, const float* __restrict__ Wih,
    const float* __restrict__ Whh, const float* __restrict__ bih,
    const float* __restrict__ bhh, const float* __restrict__ Wout,
    const float* __restrict__ bout, float* __restrict__ out)
{
  const int net = blockIdx.x >> 3, bq = blockIdx.x & 7;
  const int tid = threadIdx.x;
  const int w = tid >> 6, lane = tid & 63;
  const int quad = lane >> 4, l16 = lane & 15;

  __shared__ __bf16 hfrag[2][4][4][4][8];
  { ((int*)hfrag)[tid] = 0; }
  __syncthreads();

  bf16x8 bfrag[4][5];
  float4_t bias4[4];
#pragma unroll
  for (int g = 0; g < 4; ++g) {
    const float scale = (g == 2) ? (-2.0f*LOG2E) : (-LOG2E);
    const int col = g*NH + w*16 + l16;
#pragma unroll
    for (int kc = 0; kc < 5; ++kc) {
      const float* src = (kc == 0) ? (Wih + ((size_t)net*FH + col)*NP + quad*8)
                                   : (Whh + ((size_t)net*FH + col)*NH + (kc-1)*32 + quad*8);
      bf16x8 bf;
#pragma unroll
      for (int j = 0; j < 8; ++j) bf[j] = (__bf16)(src[j] * scale);
      bfrag[g][kc] = bf;
    }
    const float b = (bih[net*FH + col] + bhh[net*FH + col]) * scale;
    bias4[g] = (float4_t){b, b, b, b};
  }

  bf16x8 wof[4];
#pragma unroll
  for (int kc = 0; kc < 4; ++kc) {
    const float* wp = Wout + net*NH + kc*32 + quad*8;
#pragma unroll
    for (int j = 0; j < 8; ++j) wof[kc][j] = (__bf16)wp[j];
  }
  const float bo = bout[net];

  float cs = 0.f;
  const float S2 = -2.0f*LOG2E;

  const float* xrow = X + (size_t)(bq*4 + (l16 & 3))*(NT*NP) + quad*8;
  const int kcp = w >> 1, q2 = ((w & 1) << 1) | (l16 >> 3), jj = l16 & 7;
  float* outp = out + ((size_t)bq*4)*(NT*NP) + net;

  bf16x8 ax;
  {
    float xv0[8];
    *(float4_t*)&xv0[0] = *(const float4_t*)xrow;
    *(float4_t*)&xv0[4] = *(const float4_t*)(xrow + 4);
#pragma unroll
    for (int j = 0; j < 8; ++j) ax[j] = (__bf16)xv0[j];
  }
  const float* xp = xrow + NP;
  float xv[8] = {0.f,0.f,0.f,0.f,0.f,0.f,0.f,0.f};

  for (int t = 0; t < NT; ++t) {
    const int rd = t & 1, wr = rd ^ 1;
    bf16x8 ah[4];
#pragma unroll
    for (int kc = 0; kc < 4; ++kc)
      ah[kc] = *(const bf16x8*)&hfrag[rd][kc][quad][l16 & 3][0];
    float4_t accx[4];
#pragma unroll
    for (int g = 0; g < 4; ++g)
      accx[g] = mfma_bf16(ax, bfrag[g][0], bias4[g]);
    if (t + 1 < NT) {
      *(float4_t*)&xv[0] = *(const float4_t*)xp;
      *(float4_t*)&xv[4] = *(const float4_t*)(xp + 4);
    }
    float4_t acc[4];
#pragma unroll
    for (int g = 0; g < 4; ++g) {
      float4_t a0 = mfma_bf16(ah[0], bfrag[g][1], accx[g]);
      float4_t a1 = mfma_bf16(ah[2], bfrag[g][3], (float4_t){0.f,0.f,0.f,0.f});
      a0 = mfma_bf16(ah[1], bfrag[g][2], a0);
      a1 = mfma_bf16(ah[3], bfrag[g][4], a1);
      acc[g] = a0 + a1;
    }
    float gv[4];
#pragma unroll
    for (int g = 0; g < 4; ++g) {
      float a01 = (quad & 1) ? acc[g][1] : acc[g][0];
      float a23 = (quad & 1) ? acc[g][3] : acc[g][2];
      gv[g] = (quad & 2) ? a23 : a01;
    }
    float h;
    {
      float ei = __builtin_amdgcn_exp2f(gv[0]);
      float ig = __builtin_amdgcn_rcpf(1.0f + ei);
      float ef = __builtin_amdgcn_exp2f(gv[1]);
      float fg = __builtin_amdgcn_rcpf(1.0f + ef);
      float eg = __builtin_amdgcn_exp2f(fminf(gv[2], 126.0f));
      float rg = __builtin_amdgcn_rcpf(1.0f + eg);
      float t0 = S2 * rg;
      float gg2 = t0 - t0 * eg;
      float eo = __builtin_amdgcn_exp2f(gv[3]);
      float og = __builtin_amdgcn_rcpf(1.0f + eo);
      cs = fg * cs + ig * gg2;
      float ec = __builtin_amdgcn_exp2f(fminf(cs, 126.0f));
      float rc = __builtin_amdgcn_rcpf(1.0f + ec);
      float th = rc - ec * rc;
      h = og * th;
    }
    hfrag[wr][kcp][q2][quad][jj] = (__bf16)h;
    if (w == 0 && t > 0) {
      float4_t p0 = {bo, bo, bo, bo};
      float4_t p1 = {0.f, 0.f, 0.f, 0.f};
      p0 = mfma_bf16(ah[0], wof[0], p0);
      p1 = mfma_bf16(ah[2], wof[2], p1);
      p0 = mfma_bf16(ah[1], wof[1], p0);
      p1 = mfma_bf16(ah[3], wof[3], p1);
      float4_t po = p0 + p1;
      if (lane == 0) {
#pragma unroll
        for (int r = 0; r < 4; ++r)
          outp[(size_t)r*(NT*NP) + (t - 1)*NP] = po[r];
      }
    }
#pragma unroll
    for (int j = 0; j < 8; ++j) ax[j] = (__bf16)xv[j];
    xp += NP;
    BAR();
  }

  if (w == 0) {
    bf16x8 ahf[4];
#pragma unroll
    for (int kc = 0; kc < 4; ++kc)
      ahf[kc] = *(const bf16x8*)&hfrag[NT & 1][kc][quad][l16 & 3][0];
    float4_t p0 = {bo, bo, bo, bo};
    float4_t p1 = {0.f, 0.f, 0.f, 0.f};
    p0 = mfma_bf16(ahf[0], wof[0], p0);
    p1 = mfma_bf16(ahf[2], wof[2], p1);
    p0 = mfma_bf16(ahf[1], wof[1], p0);
    p1 = mfma_bf16(ahf[3], wof[3], p1);
    float4_t po = p0 + p1;
    if (lane == 0) {
#pragma unroll
      for (int r = 0; r < 4; ++r)
        outp[(size_t)r*(NT*NP) + (NT - 1)*NP] = po[r];
    }
  }
}

extern "C" void kernel_launch(void* const* d_in, const int* in_sizes, int n_in,
                              void* d_out, int out_size, void* d_ws, size_t ws_size,
                              hipStream_t stream) {
  const float* X    = (const float*)d_in[0];
  const float* Wih  = (const float*)d_in[1];
  const float* Whh  = (const float*)d_in[2];
  const float* bih  = (const float*)d_in[3];
  const float* bhh  = (const float*)d_in[4];
  const float* Wout = (const float*)d_in[5];
  const float* bout = (const float*)d_in[6];
  float* out = (float*)d_out;
  (void)in_sizes; (void)n_in; (void)out_size;

  // ws layout: [0, 512KB) X as bf16; then 256 x 256KB h-dump regions.
  const size_t nx = (size_t)NB * NT * NP;                 // X elems (bf16)
  const size_t nh = (size_t)256 * NT * 4 * NH;            // h-dump elems
  const size_t need = (nx + nh) * sizeof(__bf16);         // ~67.6 MB
  if (d_ws != nullptr && ws_size >= need) {
    __bf16* wsX = (__bf16*)d_ws;
    __bf16* wsH = wsX + nx;
    xcvt<<<128, 512, 0, stream>>>(X, wsX);
    // 256 blocks = 32 nets (XCD-swizzled) x 8 batch-groups (M=4);
    // 1 block/CU; 256-reg budget via waves_per_eu(2,2).
    clstm_fused9<<<256, 512, 0, stream>>>(wsX, Wih, Whh, bih, bhh, Wout,
                                          bout, out, wsH);
  } else {
    // R8 fallback: no workspace required.
    clstm_fused_fb<<<256, 512, 0, stream>>>(X, Wih, Whh, bih, bhh, Wout,
                                            bout, out);
  }
}

// Round 14
// 212.542 us; speedup vs baseline: 1.1464x; 1.1464x over previous
//
#include <hip/hip_runtime.h>
#include <stdint.h>

// Problem constants (match reference)
#define NP 32    // num networks (P)
#define NH 128   // hidden (H)
#define NB 32    // batch (B)
#define NT 256   // time (T)
#define FH 512   // 4*H

typedef __attribute__((ext_vector_type(4))) float float4_t;
typedef __attribute__((ext_vector_type(8))) __bf16 bf16x8;

static __device__ __forceinline__ float4_t mfma_bf16(bf16x8 a, bf16x8 b, float4_t c) {
  return __builtin_amdgcn_mfma_f32_16x16x32_bf16(a, b, c, 0, 0, 0);
}

#define LOG2E 1.4426950408889634f

// Raw workgroup barrier: drains LDS ops only (cross-wave h visibility), does
// NOT drain vmcnt — pending global loads stay in flight across it.
#define BAR() __asm__ volatile("s_waitcnt lgkmcnt(0)\n\ts_barrier" ::: "memory")

// ---------------------------------------------------------------------------
// R22: R19's loop (best, 163.6us rocprof) + f32-X direct path -> SINGLE
// kernel, no prepass, no workspace.
// R21 post-mortem: ws h-dump head-ectomy thrashed L2 (FETCH 7.3->40MB,
// MfmaUtil 47->37, +33us) — head stays fused (refuted twice, R14/R21; the
// head wave's lateness is largely absorbed by barrier slack).
// R22 rationale: xcvt prepass + 2nd launch cost ~6us of WALL time and buy
// nothing in-kernel — R19's VALUBusy is 34% (R19 proved -100 VALU cyc = +-0:
// slack), so the 8 in-loop cvts the prepass eliminated are free. x path =
// R8's proven placement: 2x dwordx4 load mid-step (full-step shadow,
// identical to R19's bf16 load), cvt at step tail, consume next step top.
// THE LOOP IS OTHERWISE FROZEN = R19: roots at top (cover ds_read latency —
// R20 showed removing them costs 16us), x-load mid-step (full shadow — R18
// showed short shadow costs 6.5us), 4 round-robin serial chains (4-way ILP —
// R17 showed segmenting costs 16us), dup-grouped A-rows (row r -> batch
// r>>2: gv = acc[0], no cndmask), XCD net swizzle (FETCH 42->7MB), rotating
// fused head, waves_per_eu(2,2) (the ONLY trusted reg knob: 256 regs).
// SESSION RULES (final form): launch_bounds 2nd arg never !=1 (R9-R11
// spill death); no DS ops in loop beyond h write/read (R5); M=4/256 blocks
// geometrically forced (R12/R14 — M=2 dup-cancellation kills any
// co-residency scheme); refuted levers: co-residency (R14), SB-stagger
// (R17), mid-chain acts (R16), tail roots (R18/R20), head-ectomy
// (R14/R21); VALU cuts below ~35% busy buy nothing (R19).
// ---------------------------------------------------------------------------
__global__ __attribute__((amdgpu_flat_work_group_size(512, 512),
                          amdgpu_waves_per_eu(2, 2)))
void clstm_fused10(
    const float* __restrict__ X, const float* __restrict__ Wih,
    const float* __restrict__ Whh, const float* __restrict__ bih,
    const float* __restrict__ bhh, const float* __restrict__ Wout,
    const float* __restrict__ bout, float* __restrict__ out)
{
  // XCD swizzle (R17-proven): blocks {n, n+32, ...} share net n and land on
  // one XCD -> weights L2-resident.
  const int net = blockIdx.x & 31, bq = blockIdx.x >> 5;
  const int tid = threadIdx.x;
  const int w = tid >> 6, lane = tid & 63;
  const int quad = lane >> 4, l16 = lane & 15;

  // h A-fragments, double buffered, 4 DISTINCT rows: [buf][kc][kquad][m<4][j]
  __shared__ __bf16 hfrag[2][4][4][4][8];   // 2 KB total

  { ((int*)hfrag)[tid] = 0; }   // h0 = 0, both buffers
  __syncthreads();

  // ---- load weights into register B-fragments (one-time) ----
  // B-frag layout for 16x16x32: lane holds B[k = quad*8 + j][n = l16].
  bf16x8 bfrag[4][5];
  float4_t bias4[4];
#pragma unroll
  for (int g = 0; g < 4; ++g) {
    const float scale = (g == 2) ? (-2.0f*LOG2E) : (-LOG2E);
    const int col = g*NH + w*16 + l16;
#pragma unroll
    for (int kc = 0; kc < 5; ++kc) {
      const float* src = (kc == 0) ? (Wih + ((size_t)net*FH + col)*NP + quad*8)
                                   : (Whh + ((size_t)net*FH + col)*NH + (kc-1)*32 + quad*8);
      bf16x8 bf;
#pragma unroll
      for (int j = 0; j < 8; ++j) bf[j] = (__bf16)(src[j] * scale);
      bfrag[g][kc] = bf;
    }
    const float b = (bih[net*FH + col] + bhh[net*FH + col]) * scale;
    bias4[g] = (float4_t){b, b, b, b};
  }

  // head B-frags (all waves — head rotates): B[k][n] = wout[k] broadcast.
  bf16x8 wof[4];
#pragma unroll
  for (int kc = 0; kc < 4; ++kc) {
    const float* wp = Wout + net*NH + kc*32 + quad*8;
#pragma unroll
    for (int j = 0; j < 8; ++j) wof[kc][j] = (__bf16)wp[j];
  }
  const float bo = bout[net];

  // c state, PRE-SCALED by -2log2e (saves a mul on the h critical chain)
  float cs = 0.f;
  const float S2 = -2.0f*LOG2E;

  // x source (f32, direct): A-row l16 -> batch bq*4 + (l16>>2)
  const float* xp = X + (size_t)(bq*4 + (l16 >> 2))*(NT*NP) + quad*8;

  // h write coords for unit u = w*16 + l16; batch row = quad (unchanged)
  const int kcp = w >> 1, q2 = ((w & 1) << 1) | (l16 >> 3), jj = l16 & 7;

  // head store base: out[(bq*4 + quad)*NT*NP + t*NP + net], stored by the
  // rotating head wave's lanes with l16==0 (C rows 4q.. = batch q dup).
  float* outp = out + ((size_t)(bq*4 + quad))*(NT*NP) + net;

  // prologue: load + convert x(0)
  bf16x8 ax;
  {
    float xv0[8];
    *(float4_t*)&xv0[0] = *(const float4_t*)xp;
    *(float4_t*)&xv0[4] = *(const float4_t*)(xp + 4);
#pragma unroll
    for (int j = 0; j < 8; ++j) ax[j] = (__bf16)xv0[j];
  }
  xp += NP;
  float xv[8] = {0.f,0.f,0.f,0.f,0.f,0.f,0.f,0.f};

// ---- one step; RD/WR literal (unroll x2). ax enters holding x(T_);
// x(T_+1) is loaded (f32) mid-step, converted at the step tail (R8-proven
// placement), consumed at the NEXT step's top: full ~1100-cyc shadow. ----
#define STEP(RD, WR, T_)                                                      \
  do {                                                                        \
    /* h A-frags (row = l16>>2; 4-lane same-address broadcast) */             \
    bf16x8 ah0 = *(const bf16x8*)&hfrag[RD][0][quad][l16 >> 2][0];            \
    bf16x8 ah1 = *(const bf16x8*)&hfrag[RD][1][quad][l16 >> 2][0];            \
    bf16x8 ah2 = *(const bf16x8*)&hfrag[RD][2][quad][l16 >> 2][0];            \
    bf16x8 ah3 = *(const bf16x8*)&hfrag[RD][3][quad][l16 >> 2][0];            \
    /* x-MFMAs first: chain roots (C = bias), no LDS dep — fill ds wait */    \
    float4_t a0 = mfma_bf16(ax, bfrag[0][0], bias4[0]);                       \
    float4_t a1 = mfma_bf16(ax, bfrag[1][0], bias4[1]);                       \
    float4_t a2 = mfma_bf16(ax, bfrag[2][0], bias4[2]);                       \
    float4_t a3 = mfma_bf16(ax, bfrag[3][0], bias4[3]);                       \
    /* x(T_+1) load, f32 (guarded; ax dead after the roots above) */          \
    if ((T_) + 1 < NT) {                                                      \
      *(float4_t*)&xv[0] = *(const float4_t*)xp;                              \
      *(float4_t*)&xv[4] = *(const float4_t*)(xp + 4);                        \
    }                                                                         \
    xp += NP;                                                                 \
    /* h-MFMAs: 4 serial chains, round-robin (4-way ILP) */                   \
    a0 = mfma_bf16(ah0, bfrag[0][1], a0);                                     \
    a1 = mfma_bf16(ah0, bfrag[1][1], a1);                                     \
    a2 = mfma_bf16(ah0, bfrag[2][1], a2);                                     \
    a3 = mfma_bf16(ah0, bfrag[3][1], a3);                                     \
    a0 = mfma_bf16(ah1, bfrag[0][2], a0);                                     \
    a1 = mfma_bf16(ah1, bfrag[1][2], a1);                                     \
    a2 = mfma_bf16(ah1, bfrag[2][2], a2);                                     \
    a3 = mfma_bf16(ah1, bfrag[3][2], a3);                                     \
    a0 = mfma_bf16(ah2, bfrag[0][3], a0);                                     \
    a1 = mfma_bf16(ah2, bfrag[1][3], a1);                                     \
    a2 = mfma_bf16(ah2, bfrag[2][3], a2);                                     \
    a3 = mfma_bf16(ah2, bfrag[3][3], a3);                                     \
    a0 = mfma_bf16(ah3, bfrag[0][4], a0);                                     \
    a1 = mfma_bf16(ah3, bfrag[1][4], a1);                                     \
    a2 = mfma_bf16(ah3, bfrag[2][4], a2);                                     \
    a3 = mfma_bf16(ah3, bfrag[3][4], a3);                                     \
    /* acts: gv = acc[0] (dup-grouped rows — no cndmask select) */            \
    float ei = __builtin_amdgcn_exp2f(a0[0]);                                 \
    float ig = __builtin_amdgcn_rcpf(1.0f + ei);          /* sigmoid(i) */    \
    float ef = __builtin_amdgcn_exp2f(a1[0]);                                 \
    float fg = __builtin_amdgcn_rcpf(1.0f + ef);          /* sigmoid(f) */    \
    float eg = __builtin_amdgcn_exp2f(fminf(a2[0], 126.0f));                  \
    float rg = __builtin_amdgcn_rcpf(1.0f + eg);                              \
    float t0 = S2 * rg;                                                       \
    float gg2 = t0 - t0 * eg;                             /* tanh(g)*S2 */    \
    float eo = __builtin_amdgcn_exp2f(a3[0]);                                 \
    float og = __builtin_amdgcn_rcpf(1.0f + eo);          /* sigmoid(o) */    \
    cs = fg * cs + ig * gg2;                              /* c * S2 */        \
    float ec = __builtin_amdgcn_exp2f(fminf(cs, 126.0f));                     \
    float rc = __builtin_amdgcn_rcpf(1.0f + ec);                              \
    float h_ = og * (rc - ec * rc);                       /* o*tanh(c) */     \
    /* write h' (bf16): 1 ds_write_b16, batch row = quad */                   \
    hfrag[WR][kcp][q2][quad][jj] = (__bf16)h_;                                \
    /* rotating fused head (ah = h_{t-1} -> out[t-1]); per-quad store */      \
    if ((T_) > 0 && w == ((T_) & 7)) {                                        \
      float4_t p0 = {bo, bo, bo, bo};                                         \
      float4_t p1 = {0.f, 0.f, 0.f, 0.f};                                     \
      p0 = mfma_bf16(ah0, wof[0], p0);                                        \
      p1 = mfma_bf16(ah2, wof[2], p1);                                        \
      p0 = mfma_bf16(ah1, wof[1], p0);                                        \
      p1 = mfma_bf16(ah3, wof[3], p1);                                        \
      if (l16 == 0)                                                           \
        outp[(size_t)((T_) - 1)*NP] = p0[0] + p1[0];                          \
    }                                                                         \
    /* tail: convert x(T_+1) (load landed long ago; VALU slack absorbs) */    \
    _Pragma("unroll")                                                         \
    for (int j = 0; j < 8; ++j) ax[j] = (__bf16)xv[j];                        \
    BAR();                                                                    \
  } while (0)

  for (int t = 0; t < NT; t += 2) {
    STEP(0, 1, t);
    STEP(1, 0, t + 1);
  }
#undef STEP

  // ---- epilogue: head for t = NT-1 (h_{NT-1} is in hfrag[NT&1]) ----
  if (w == 0) {
    bf16x8 ahf[4];
#pragma unroll
    for (int kc = 0; kc < 4; ++kc)
      ahf[kc] = *(const bf16x8*)&hfrag[NT & 1][kc][quad][l16 >> 2][0];
    float4_t p0 = {bo, bo, bo, bo};
    float4_t p1 = {0.f, 0.f, 0.f, 0.f};
    p0 = mfma_bf16(ahf[0], wof[0], p0);
    p1 = mfma_bf16(ahf[2], wof[2], p1);
    p0 = mfma_bf16(ahf[1], wof[1], p0);
    p1 = mfma_bf16(ahf[3], wof[3], p1);
    if (l16 == 0)
      outp[(size_t)(NT - 1)*NP] = p0[0] + p1[0];
  }
}

extern "C" void kernel_launch(void* const* d_in, const int* in_sizes, int n_in,
                              void* d_out, int out_size, void* d_ws, size_t ws_size,
                              hipStream_t stream) {
  const float* X    = (const float*)d_in[0];
  const float* Wih  = (const float*)d_in[1];
  const float* Whh  = (const float*)d_in[2];
  const float* bih  = (const float*)d_in[3];
  const float* bhh  = (const float*)d_in[4];
  const float* Wout = (const float*)d_in[5];
  const float* bout = (const float*)d_in[6];
  float* out = (float*)d_out;
  (void)in_sizes; (void)n_in; (void)out_size; (void)d_ws; (void)ws_size;

  // Single launch: 256 blocks = 32 nets (XCD-swizzled) x 8 batch-groups
  // (M=4); 1 block/CU; 256-reg budget via waves_per_eu(2,2). No prepass,
  // no workspace.
  clstm_fused10<<<256, 512, 0, stream>>>(X, Wih, Whh, bih, bhh, Wout,
                                         bout, out);
}

// Round 15
// 208.561 us; speedup vs baseline: 1.1683x; 1.0191x over previous
//
#include <hip/hip_runtime.h>
#include <stdint.h>

// Problem constants (match reference)
#define NP 32    // num networks (P)
#define NH 128   // hidden (H)
#define NB 32    // batch (B)
#define NT 256   // time (T)
#define FH 512   // 4*H

typedef __attribute__((ext_vector_type(4))) float float4_t;
typedef __attribute__((ext_vector_type(8))) __bf16 bf16x8;
typedef __attribute__((ext_vector_type(4))) __bf16 bf16x4;

static __device__ __forceinline__ float4_t mfma_bf16(bf16x8 a, bf16x8 b, float4_t c) {
  return __builtin_amdgcn_mfma_f32_16x16x32_bf16(a, b, c, 0, 0, 0);
}

#define LOG2E 1.4426950408889634f

// Raw workgroup barrier: drains LDS ops only (cross-wave h visibility), does
// NOT drain vmcnt — pending global loads/stores stay in flight across it.
#define BAR() __asm__ volatile("s_waitcnt lgkmcnt(0)\n\ts_barrier" ::: "memory")

// ---------------------------------------------------------------------------
// R23: restore R19 exactly (best: 163.6us rocprof / 207.2us harness) +
// EARLY HEAD ISSUE.
// R22 post-mortem: f32-direct X regressed ~5us (FETCH 7.3->9.3MB; tail
// cvts sit ON the tail-to-barrier path — "VALU slack" only covers ops off
// that path). xcvt prepass + bf16 loads restored.
// R23's single delta vs R19: the rotating head wave currently issues its 4
// head MFMAs at the tail and scoreboard-WAITS ~100-140cyc for results
// before storing -> all 16 waves convoy at BAR behind it, every step.
// Move the head-MFMA issue to mid-step (right after the x reload; ah0-3
// live, roots already issued so the ds-latency cover is intact) and keep
// only the store at the tail: results ready ~1000cyc before the store, so
// the tail wait vanishes (~-60cyc/step). Issue-position lateness (~77cyc,
// 24 vs 20 MFMAs on that SIMD) remains — unavoidable.
// FROZEN SKELETON (R19): ah loads -> x-roots (C=bias, cover ds_read —
// R20: removing costs 16us) -> x reload (full-step shadow — R18: short
// shadow costs 6.5us) -> 4 round-robin serial chains (4-way ILP — R17:
// segmenting costs 16us) -> acts (gv=acc[0], dup-grouped rows) -> h write.
// XCD net swizzle (FETCH 42->7MB). waves_per_eu(2,2) = only trusted reg
// knob (256 regs).
// SESSION RULES (final): launch_bounds 2nd arg never !=1 (R9-R11 spill
// death); no DS ops in loop beyond h write/read (R5); M=4/256 blocks
// geometrically forced (R12/R14); refuted: co-residency (R14), SB-stagger
// (R17), mid-chain acts (R16), tail roots (R18/R20), head-ectomy
// (R14/R21), f32-direct X (R22); VALU cuts below ~35% busy buy nothing
// (R19). If this round lands ~163-165 => convoy absorbed => structural
// floor reached => ROOFLINE.
// ---------------------------------------------------------------------------

// Prepass: X f32 -> bf16 into ws (same [B][T][P] layout). 262144 elems.
__global__ __launch_bounds__(512, 1) void xcvt(
    const float* __restrict__ X, __bf16* __restrict__ Xb)
{
  const int i = (blockIdx.x * 512 + threadIdx.x) * 4;
  float4_t v = *(const float4_t*)(X + i);
  bf16x4 o;
#pragma unroll
  for (int j = 0; j < 4; ++j) o[j] = (__bf16)v[j];
  *(bf16x4*)(Xb + i) = o;
}

__global__ __attribute__((amdgpu_flat_work_group_size(512, 512),
                          amdgpu_waves_per_eu(2, 2)))
void clstm_fused11(
    const __bf16* __restrict__ Xb, const float* __restrict__ Wih,
    const float* __restrict__ Whh, const float* __restrict__ bih,
    const float* __restrict__ bhh, const float* __restrict__ Wout,
    const float* __restrict__ bout, float* __restrict__ out)
{
  // XCD swizzle (R17-proven): blocks {n, n+32, ...} share net n and land on
  // one XCD -> weights L2-resident.
  const int net = blockIdx.x & 31, bq = blockIdx.x >> 5;
  const int tid = threadIdx.x;
  const int w = tid >> 6, lane = tid & 63;
  const int quad = lane >> 4, l16 = lane & 15;

  // h A-fragments, double buffered, 4 DISTINCT rows: [buf][kc][kquad][m<4][j]
  __shared__ __bf16 hfrag[2][4][4][4][8];   // 2 KB total

  { ((int*)hfrag)[tid] = 0; }   // h0 = 0, both buffers
  __syncthreads();

  // ---- load weights into register B-fragments (one-time) ----
  // B-frag layout for 16x16x32: lane holds B[k = quad*8 + j][n = l16].
  bf16x8 bfrag[4][5];
  float4_t bias4[4];
#pragma unroll
  for (int g = 0; g < 4; ++g) {
    const float scale = (g == 2) ? (-2.0f*LOG2E) : (-LOG2E);
    const int col = g*NH + w*16 + l16;
#pragma unroll
    for (int kc = 0; kc < 5; ++kc) {
      const float* src = (kc == 0) ? (Wih + ((size_t)net*FH + col)*NP + quad*8)
                                   : (Whh + ((size_t)net*FH + col)*NH + (kc-1)*32 + quad*8);
      bf16x8 bf;
#pragma unroll
      for (int j = 0; j < 8; ++j) bf[j] = (__bf16)(src[j] * scale);
      bfrag[g][kc] = bf;
    }
    const float b = (bih[net*FH + col] + bhh[net*FH + col]) * scale;
    bias4[g] = (float4_t){b, b, b, b};
  }

  // head B-frags (all waves — head rotates): B[k][n] = wout[k] broadcast.
  bf16x8 wof[4];
#pragma unroll
  for (int kc = 0; kc < 4; ++kc) {
    const float* wp = Wout + net*NH + kc*32 + quad*8;
#pragma unroll
    for (int j = 0; j < 8; ++j) wof[kc][j] = (__bf16)wp[j];
  }
  const float bo = bout[net];

  // c state, PRE-SCALED by -2log2e (saves a mul on the h critical chain)
  float cs = 0.f;
  const float S2 = -2.0f*LOG2E;

  // x source: A-row l16 -> batch bq*4 + (l16>>2)  (dup-grouped rows)
  int xoff = (bq*4 + (l16 >> 2))*(NT*NP) + quad*8;

  // h write coords for unit u = w*16 + l16; batch row = quad (unchanged)
  const int kcp = w >> 1, q2 = ((w & 1) << 1) | (l16 >> 3), jj = l16 & 7;

  // head store base: out[(bq*4 + quad)*NT*NP + t*NP + net], stored by the
  // rotating head wave's lanes with l16==0 (C rows 4q.. = batch q dup).
  float* outp = out + ((size_t)(bq*4 + quad))*(NT*NP) + net;

  // prologue: ax = x(0)
  bf16x8 ax = *(const bf16x8*)(Xb + xoff);
  xoff += NP;

// ---- one step; RD/WR literal (unroll x2). ax enters holding x(T_);
// x(T_+1) is loaded mid-step and consumed at the NEXT step's top (full
// ~1100cyc shadow). Head MFMAs issue EARLY (mid-step); only the store is
// at the tail — no result-wait before BAR. ----
#define STEP(RD, WR, T_)                                                      \
  do {                                                                        \
    /* h A-frags (row = l16>>2; 4-lane same-address broadcast) */             \
    bf16x8 ah0 = *(const bf16x8*)&hfrag[RD][0][quad][l16 >> 2][0];            \
    bf16x8 ah1 = *(const bf16x8*)&hfrag[RD][1][quad][l16 >> 2][0];            \
    bf16x8 ah2 = *(const bf16x8*)&hfrag[RD][2][quad][l16 >> 2][0];            \
    bf16x8 ah3 = *(const bf16x8*)&hfrag[RD][3][quad][l16 >> 2][0];            \
    /* x-MFMAs first: chain roots (C = bias), no LDS dep — fill ds wait */    \
    float4_t a0 = mfma_bf16(ax, bfrag[0][0], bias4[0]);                       \
    float4_t a1 = mfma_bf16(ax, bfrag[1][0], bias4[1]);                       \
    float4_t a2 = mfma_bf16(ax, bfrag[2][0], bias4[2]);                       \
    float4_t a3 = mfma_bf16(ax, bfrag[3][0], bias4[3]);                       \
    /* x reload for t+1 (guarded; ax dead after the roots above) */           \
    if ((T_) + 1 < NT)                                                        \
      ax = *(const bf16x8*)(Xb + xoff);                                       \
    xoff += NP;                                                               \
    /* EARLY head issue (rotating wave): 2 indep 2-deep chains; results */    \
    /* ready ~1000cyc before the tail store — zero wait at BAR. */            \
    float4_t p0 = {bo, bo, bo, bo};                                           \
    float4_t p1 = {0.f, 0.f, 0.f, 0.f};                                       \
    if ((T_) > 0 && w == ((T_) & 7)) {                                        \
      p0 = mfma_bf16(ah0, wof[0], p0);                                        \
      p1 = mfma_bf16(ah2, wof[2], p1);                                        \
      p0 = mfma_bf16(ah1, wof[1], p0);                                        \
      p1 = mfma_bf16(ah3, wof[3], p1);                                        \
    }                                                                         \
    /* h-MFMAs: 4 serial chains, round-robin (4-way ILP) */                   \
    a0 = mfma_bf16(ah0, bfrag[0][1], a0);                                     \
    a1 = mfma_bf16(ah0, bfrag[1][1], a1);                                     \
    a2 = mfma_bf16(ah0, bfrag[2][1], a2);                                     \
    a3 = mfma_bf16(ah0, bfrag[3][1], a3);                                     \
    a0 = mfma_bf16(ah1, bfrag[0][2], a0);                                     \
    a1 = mfma_bf16(ah1, bfrag[1][2], a1);                                     \
    a2 = mfma_bf16(ah1, bfrag[2][2], a2);                                     \
    a3 = mfma_bf16(ah1, bfrag[3][2], a3);                                     \
    a0 = mfma_bf16(ah2, bfrag[0][3], a0);                                     \
    a1 = mfma_bf16(ah2, bfrag[1][3], a1);                                     \
    a2 = mfma_bf16(ah2, bfrag[2][3], a2);                                     \
    a3 = mfma_bf16(ah2, bfrag[3][3], a3);                                     \
    a0 = mfma_bf16(ah3, bfrag[0][4], a0);                                     \
    a1 = mfma_bf16(ah3, bfrag[1][4], a1);                                     \
    a2 = mfma_bf16(ah3, bfrag[2][4], a2);                                     \
    a3 = mfma_bf16(ah3, bfrag[3][4], a3);                                     \
    /* acts: gv = acc[0] (dup-grouped rows — no cndmask select) */            \
    float ei = __builtin_amdgcn_exp2f(a0[0]);                                 \
    float ig = __builtin_amdgcn_rcpf(1.0f + ei);          /* sigmoid(i) */    \
    float ef = __builtin_amdgcn_exp2f(a1[0]);                                 \
    float fg = __builtin_amdgcn_rcpf(1.0f + ef);          /* sigmoid(f) */    \
    float eg = __builtin_amdgcn_exp2f(fminf(a2[0], 126.0f));                  \
    float rg = __builtin_amdgcn_rcpf(1.0f + eg);                              \
    float t0 = S2 * rg;                                                       \
    float gg2 = t0 - t0 * eg;                             /* tanh(g)*S2 */    \
    float eo = __builtin_amdgcn_exp2f(a3[0]);                                 \
    float og = __builtin_amdgcn_rcpf(1.0f + eo);          /* sigmoid(o) */    \
    cs = fg * cs + ig * gg2;                              /* c * S2 */        \
    float ec = __builtin_amdgcn_exp2f(fminf(cs, 126.0f));                     \
    float rc = __builtin_amdgcn_rcpf(1.0f + ec);                              \
    float h_ = og * (rc - ec * rc);                       /* o*tanh(c) */     \
    /* write h' (bf16): 1 ds_write_b16, batch row = quad */                   \
    hfrag[WR][kcp][q2][quad][jj] = (__bf16)h_;                                \
    /* head store only (results long ready; no scoreboard wait) */            \
    if ((T_) > 0 && w == ((T_) & 7) && l16 == 0)                              \
      outp[(size_t)((T_) - 1)*NP] = p0[0] + p1[0];                            \
    BAR();                                                                    \
  } while (0)

  for (int t = 0; t < NT; t += 2) {
    STEP(0, 1, t);
    STEP(1, 0, t + 1);
  }
#undef STEP

  // ---- epilogue: head for t = NT-1 (h_{NT-1} is in hfrag[NT&1]) ----
  if (w == 0) {
    bf16x8 ahf[4];
#pragma unroll
    for (int kc = 0; kc < 4; ++kc)
      ahf[kc] = *(const bf16x8*)&hfrag[NT & 1][kc][quad][l16 >> 2][0];
    float4_t p0 = {bo, bo, bo, bo};
    float4_t p1 = {0.f, 0.f, 0.f, 0.f};
    p0 = mfma_bf16(ahf[0], wof[0], p0);
    p1 = mfma_bf16(ahf[2], wof[2], p1);
    p0 = mfma_bf16(ahf[1], wof[1], p0);
    p1 = mfma_bf16(ahf[3], wof[3], p1);
    if (l16 == 0)
      outp[(size_t)(NT - 1)*NP] = p0[0] + p1[0];
  }
}

// ---------------------------------------------------------------------------
// Fallback (ws too small): R8 kernel verbatim — M=4 / 256 blocks, fused
// head, f32 X loads, 219us rocprof. No workspace use.
// ---------------------------------------------------------------------------
__global__ __launch_bounds__(512, 1) void clstm_fused_fb(
    const float* __restrict__ X, const float* __restrict__ Wih,
    const float* __restrict__ Whh, const float* __restrict__ bih,
    const float* __restrict__ bhh, const float* __restrict__ Wout,
    const float* __restrict__ bout, float* __restrict__ out)
{
  const int net = blockIdx.x >> 3, bq = blockIdx.x & 7;
  const int tid = threadIdx.x;
  const int w = tid >> 6, lane = tid & 63;
  const int quad = lane >> 4, l16 = lane & 15;

  __shared__ __bf16 hfrag[2][4][4][4][8];
  { ((int*)hfrag)[tid] = 0; }
  __syncthreads();

  bf16x8 bfrag[4][5];
  float4_t bias4[4];
#pragma unroll
  for (int g = 0; g < 4; ++g) {
    const float scale = (g == 2) ? (-2.0f*LOG2E) : (-LOG2E);
    const int col = g*NH + w*16 + l16;
#pragma unroll
    for (int kc = 0; kc < 5; ++kc) {
      const float* src = (kc == 0) ? (Wih + ((size_t)net*FH + col)*NP + quad*8)
                                   : (Whh + ((size_t)net*FH + col)*NH + (kc-1)*32 + quad*8);
      bf16x8 bf;
#pragma unroll
      for (int j = 0; j < 8; ++j) bf[j] = (__bf16)(src[j] * scale);
      bfrag[g][kc] = bf;
    }
    const float b = (bih[net*FH + col] + bhh[net*FH + col]) * scale;
    bias4[g] = (float4_t){b, b, b, b};
  }

  bf16x8 wof[4];
#pragma unroll
  for (int kc = 0; kc < 4; ++kc) {
    const float* wp = Wout + net*NH + kc*32 + quad*8;
#pragma unroll
    for (int j = 0; j < 8; ++j) wof[kc][j] = (__bf16)wp[j];
  }
  const float bo = bout[net];

  float cs = 0.f;
  const float S2 = -2.0f*LOG2E;

  const float* xrow = X + (size_t)(bq*4 + (l16 & 3))*(NT*NP) + quad*8;
  const int kcp = w >> 1, q2 = ((w & 1) << 1) | (l16 >> 3), jj = l16 & 7;
  float* outp = out + ((size_t)bq*4)*(NT*NP) + net;

  bf16x8 ax;
  {
    float xv0[8];
    *(float4_t*)&xv0[0] = *(const float4_t*)xrow;
    *(float4_t*)&xv0[4] = *(const float4_t*)(xrow + 4);
#pragma unroll
    for (int j = 0; j < 8; ++j) ax[j] = (__bf16)xv0[j];
  }
  const float* xp = xrow + NP;
  float xv[8] = {0.f,0.f,0.f,0.f,0.f,0.f,0.f,0.f};

  for (int t = 0; t < NT; ++t) {
    const int rd = t & 1, wr = rd ^ 1;
    bf16x8 ah[4];
#pragma unroll
    for (int kc = 0; kc < 4; ++kc)
      ah[kc] = *(const bf16x8*)&hfrag[rd][kc][quad][l16 & 3][0];
    float4_t accx[4];
#pragma unroll
    for (int g = 0; g < 4; ++g)
      accx[g] = mfma_bf16(ax, bfrag[g][0], bias4[g]);
    if (t + 1 < NT) {
      *(float4_t*)&xv[0] = *(const float4_t*)xp;
      *(float4_t*)&xv[4] = *(const float4_t*)(xp + 4);
    }
    float4_t acc[4];
#pragma unroll
    for (int g = 0; g < 4; ++g) {
      float4_t a0 = mfma_bf16(ah[0], bfrag[g][1], accx[g]);
      float4_t a1 = mfma_bf16(ah[2], bfrag[g][3], (float4_t){0.f,0.f,0.f,0.f});
      a0 = mfma_bf16(ah[1], bfrag[g][2], a0);
      a1 = mfma_bf16(ah[3], bfrag[g][4], a1);
      acc[g] = a0 + a1;
    }
    float gv[4];
#pragma unroll
    for (int g = 0; g < 4; ++g) {
      float a01 = (quad & 1) ? acc[g][1] : acc[g][0];
      float a23 = (quad & 1) ? acc[g][3] : acc[g][2];
      gv[g] = (quad & 2) ? a23 : a01;
    }
    float h;
    {
      float ei = __builtin_amdgcn_exp2f(gv[0]);
      float ig = __builtin_amdgcn_rcpf(1.0f + ei);
      float ef = __builtin_amdgcn_exp2f(gv[1]);
      float fg = __builtin_amdgcn_rcpf(1.0f + ef);
      float eg = __builtin_amdgcn_exp2f(fminf(gv[2], 126.0f));
      float rg = __builtin_amdgcn_rcpf(1.0f + eg);
      float t0 = S2 * rg;
      float gg2 = t0 - t0 * eg;
      float eo = __builtin_amdgcn_exp2f(gv[3]);
      float og = __builtin_amdgcn_rcpf(1.0f + eo);
      cs = fg * cs + ig * gg2;
      float ec = __builtin_amdgcn_exp2f(fminf(cs, 126.0f));
      float rc = __builtin_amdgcn_rcpf(1.0f + ec);
      float th = rc - ec * rc;
      h = og * th;
    }
    hfrag[wr][kcp][q2][quad][jj] = (__bf16)h;
    if (w == 0 && t > 0) {
      float4_t p0 = {bo, bo, bo, bo};
      float4_t p1 = {0.f, 0.f, 0.f, 0.f};
      p0 = mfma_bf16(ah[0], wof[0], p0);
      p1 = mfma_bf16(ah[2], wof[2], p1);
      p0 = mfma_bf16(ah[1], wof[1], p0);
      p1 = mfma_bf16(ah[3], wof[3], p1);
      float4_t po = p0 + p1;
      if (lane == 0) {
#pragma unroll
        for (int r = 0; r < 4; ++r)
          outp[(size_t)r*(NT*NP) + (t - 1)*NP] = po[r];
      }
    }
#pragma unroll
    for (int j = 0; j < 8; ++j) ax[j] = (__bf16)xv[j];
    xp += NP;
    BAR();
  }

  if (w == 0) {
    bf16x8 ahf[4];
#pragma unroll
    for (int kc = 0; kc < 4; ++kc)
      ahf[kc] = *(const bf16x8*)&hfrag[NT & 1][kc][quad][l16 & 3][0];
    float4_t p0 = {bo, bo, bo, bo};
    float4_t p1 = {0.f, 0.f, 0.f, 0.f};
    p0 = mfma_bf16(ahf[0], wof[0], p0);
    p1 = mfma_bf16(ahf[2], wof[2], p1);
    p0 = mfma_bf16(ahf[1], wof[1], p0);
    p1 = mfma_bf16(ahf[3], wof[3], p1);
    float4_t po = p0 + p1;
    if (lane == 0) {
#pragma unroll
      for (int r = 0; r < 4; ++r)
        outp[(size_t)r*(NT*NP) + (NT - 1)*NP] = po[r];
    }
  }
}

extern "C" void kernel_launch(void* const* d_in, const int* in_sizes, int n_in,
                              void* d_out, int out_size, void* d_ws, size_t ws_size,
                              hipStream_t stream) {
  const float* X    = (const float*)d_in[0];
  const float* Wih  = (const float*)d_in[1];
  const float* Whh  = (const float*)d_in[2];
  const float* bih  = (const float*)d_in[3];
  const float* bhh  = (const float*)d_in[4];
  const float* Wout = (const float*)d_in[5];
  const float* bout = (const float*)d_in[6];
  float* out = (float*)d_out;
  (void)in_sizes; (void)n_in; (void)out_size;

  // ws layout: [0, 512KB) X as bf16.
  const size_t need = (size_t)NB*NT*NP*2;
  if (d_ws != nullptr && ws_size >= need) {
    __bf16* wsX = (__bf16*)d_ws;
    xcvt<<<128, 512, 0, stream>>>(X, wsX);
    // 256 blocks = 32 nets (XCD-swizzled) x 8 batch-groups (M=4);
    // 1 block/CU; 256-reg budget via waves_per_eu(2,2).
    clstm_fused11<<<256, 512, 0, stream>>>(wsX, Wih, Whh, bih, bhh, Wout,
                                           bout, out);
  } else {
    // R8 fallback: no workspace required.
    clstm_fused_fb<<<256, 512, 0, stream>>>(X, Wih, Whh, bih, bhh, Wout,
                                            bout, out);
  }
}